// Round 1
// baseline (291.150 us; speedup 1.0000x reference)
//
#include <hip/hip_runtime.h>

// Row-wise metadata for irreps l = 0..7 (DIM = 64).
// M = l^2 + (m + l);  |m|, sign(m), and partner index neg(M) = 2(l^2+l) - M.
__constant__ int c_am[64] = {
  0,
  1,0,1,
  2,1,0,1,2,
  3,2,1,0,1,2,3,
  4,3,2,1,0,1,2,3,4,
  5,4,3,2,1,0,1,2,3,4,5,
  6,5,4,3,2,1,0,1,2,3,4,5,6,
  7,6,5,4,3,2,1,0,1,2,3,4,5,6,7
};
__constant__ float c_sign[64] = {
  0.f,
  -1.f,0.f,1.f,
  -1.f,-1.f,0.f,1.f,1.f,
  -1.f,-1.f,-1.f,0.f,1.f,1.f,1.f,
  -1.f,-1.f,-1.f,-1.f,0.f,1.f,1.f,1.f,1.f,
  -1.f,-1.f,-1.f,-1.f,-1.f,0.f,1.f,1.f,1.f,1.f,1.f,
  -1.f,-1.f,-1.f,-1.f,-1.f,-1.f,0.f,1.f,1.f,1.f,1.f,1.f,1.f,
  -1.f,-1.f,-1.f,-1.f,-1.f,-1.f,-1.f,0.f,1.f,1.f,1.f,1.f,1.f,1.f,1.f
};
__constant__ int c_neg[64] = {
  0,
  3,2,1,
  8,7,6,5,4,
  15,14,13,12,11,10,9,
  24,23,22,21,20,19,18,17,16,
  35,34,33,32,31,30,29,28,27,26,25,
  48,47,46,45,44,43,42,41,40,39,38,37,36,
  63,62,61,60,59,58,57,56,55,54,53,52,51,50,49
};

// One block per sample n. Tile = DIM x C = 64 x 64 fp32 = 16 KB = 1024 float4.
// 256 threads x 4 float4 each. float4 index f: row M = f>>4, col4 = f&15.
__global__ __launch_bounds__(256) void wigner_z_kernel(
    const float4* __restrict__ x, const float* __restrict__ angle,
    float4* __restrict__ out, int N) {
  __shared__ float s_sin[8];
  __shared__ float s_cos[8];

  const int n = blockIdx.x;
  if (n >= N) return;
  const int t = threadIdx.x;

  if (t < 8) {
    float s, c;
    sincosf((float)t * angle[n], &s, &c);  // t=0 -> (0,1)
    s_sin[t] = s;
    s_cos[t] = c;
  }
  __syncthreads();

  const float4* xb = x + (size_t)n * 1024;
  float4* ob = out + (size_t)n * 1024;

#pragma unroll
  for (int k = 0; k < 4; ++k) {
    const int f = t + k * 256;
    const int M = f >> 4;
    const int c4 = f & 15;
    const int am = c_am[M];
    const float co = s_cos[am];
    const float si = c_sign[M] * s_sin[am];

    const float4 a = xb[f];
    const float4 b = xb[(c_neg[M] << 4) | c4];

    float4 o;
    o.x = co * a.x - si * b.x;
    o.y = co * a.y - si * b.y;
    o.z = co * a.z - si * b.z;
    o.w = co * a.w - si * b.w;
    ob[f] = o;
  }
}

extern "C" void kernel_launch(void* const* d_in, const int* in_sizes, int n_in,
                              void* d_out, int out_size, void* d_ws, size_t ws_size,
                              hipStream_t stream) {
  const float4* x = (const float4*)d_in[0];
  const float* angle = (const float*)d_in[1];
  float4* out = (float4*)d_out;
  const int N = in_sizes[1];  // angle has one entry per sample

  wigner_z_kernel<<<N, 256, 0, stream>>>(x, angle, out, N);
}

// Round 2
// 276.110 us; speedup vs baseline: 1.0545x; 1.0545x over previous
//
#include <hip/hip_runtime.h>

// Irreps l=0..7, DIM=64. Pair tables: for each l, m=1..l,
// M+ = l^2+l+m (sign=+1), M- = l^2+l-m (sign=-1). 28 pairs + 8 m==0 rows.
__constant__ int P_A[28] = {
  3, 7,8, 13,14,15, 21,22,23,24, 31,32,33,34,35,
  43,44,45,46,47,48, 57,58,59,60,61,62,63
};
__constant__ int P_B[28] = {
  1, 5,4, 11,10,9, 19,18,17,16, 29,28,27,26,25,
  41,40,39,38,37,36, 55,54,53,52,51,50,49
};
__constant__ int P_AM[28] = {
  1, 1,2, 1,2,3, 1,2,3,4, 1,2,3,4,5, 1,2,3,4,5,6, 1,2,3,4,5,6,7
};
__constant__ int S_R[8] = {0,2,6,12,20,30,42,56};  // m==0 rows (identity copy)

// One block per sample n. Tile = 64x64 fp32 = 1024 float4.
// 576 threads: 448 (7 waves) handle the 28 pairs x 16 float4-cols,
// 128 (2 waves) copy the 8 m==0 rows. Every float4 loaded/stored exactly once.
__global__ __launch_bounds__(576) void wigner_z_pair_kernel(
    const float4* __restrict__ x, const float* __restrict__ angle,
    float4* __restrict__ out, int N) {
  __shared__ float s_sin[8];
  __shared__ float s_cos[8];

  const int n = blockIdx.x;
  const int t = threadIdx.x;

  if (t < 8) {
    float s, c;
    sincosf((float)t * angle[n], &s, &c);  // t=0 -> (0,1), unused
    s_sin[t] = s;
    s_cos[t] = c;
  }
  __syncthreads();

  const float4* __restrict__ xb = x + (size_t)n * 1024;
  float4* __restrict__ ob = out + (size_t)n * 1024;

  if (t < 448) {
    const int p = t >> 4;
    const int c4 = t & 15;
    const int fa = (P_A[p] << 4) | c4;
    const int fb = (P_B[p] << 4) | c4;
    const int am = P_AM[p];
    const float co = s_cos[am];
    const float si = s_sin[am];

    const float4 a = xb[fa];
    const float4 b = xb[fb];

    float4 oa, obv;
    oa.x = co * a.x - si * b.x;
    oa.y = co * a.y - si * b.y;
    oa.z = co * a.z - si * b.z;
    oa.w = co * a.w - si * b.w;
    obv.x = co * b.x + si * a.x;
    obv.y = co * b.y + si * a.y;
    obv.z = co * b.z + si * a.z;
    obv.w = co * b.w + si * a.w;
    ob[fa] = oa;
    ob[fb] = obv;
  } else {
    const int q = t - 448;
    const int f = (S_R[q >> 4] << 4) | (q & 15);
    ob[f] = xb[f];  // m == 0: identity
  }
}

extern "C" void kernel_launch(void* const* d_in, const int* in_sizes, int n_in,
                              void* d_out, int out_size, void* d_ws, size_t ws_size,
                              hipStream_t stream) {
  const float4* x = (const float4*)d_in[0];
  const float* angle = (const float*)d_in[1];
  float4* out = (float4*)d_out;
  const int N = in_sizes[1];  // one angle per sample

  wigner_z_pair_kernel<<<N, 576, 0, stream>>>(x, angle, out, N);
}

// Round 4
// 273.279 us; speedup vs baseline: 1.0654x; 1.0104x over previous
//
#include <hip/hip_runtime.h>

typedef float vfloat4 __attribute__((ext_vector_type(4)));

// Irreps l=0..7, DIM=64. 32 generalized pairs:
//  - 28 real pairs (M+ = l^2+l+m, M- = l^2+l-m, m=1..l), factor angle m.
//  - 4 pseudo-pairs covering the 8 m==0 rows with am=0 (cos=1, sin=0 -> identity).
__constant__ int P_A[32] = {
  3, 7,8, 13,14,15, 21,22,23,24, 31,32,33,34,35,
  43,44,45,46,47,48, 57,58,59,60,61,62,63,
  0, 6, 20, 42
};
__constant__ int P_B[32] = {
  1, 5,4, 11,10,9, 19,18,17,16, 29,28,27,26,25,
  41,40,39,38,37,36, 55,54,53,52,51,50,49,
  2, 12, 30, 56
};
__constant__ int P_AM[32] = {
  1, 1,2, 1,2,3, 1,2,3,4, 1,2,3,4,5, 1,2,3,4,5,6, 1,2,3,4,5,6,7,
  0, 0, 0, 0
};

// One block per sample n. Tile = 64x64 fp32 = 1024 float4.
// 512 threads = 32 pairs x 16 float4-cols; each thread: 2 loads, 2 stores.
// Uniform control flow; 8-wave blocks -> 4 blocks/CU -> 32/32 waves.
__global__ __launch_bounds__(512) void wigner_z_pair2_kernel(
    const vfloat4* __restrict__ x, const float* __restrict__ angle,
    vfloat4* __restrict__ out, int N) {
  __shared__ float s_sin[8];
  __shared__ float s_cos[8];

  const int n = blockIdx.x;
  const int t = threadIdx.x;

  if (t < 8) {
    float s, c;
    sincosf((float)t * angle[n], &s, &c);  // t=0 -> (0,1)
    s_sin[t] = s;
    s_cos[t] = c;
  }
  __syncthreads();

  const vfloat4* __restrict__ xb = x + (size_t)n * 1024;
  vfloat4* __restrict__ ob = out + (size_t)n * 1024;

  const int p = t >> 4;
  const int c4 = t & 15;
  const int fa = (P_A[p] << 4) | c4;
  const int fb = (P_B[p] << 4) | c4;
  const int am = P_AM[p];
  const float co = s_cos[am];
  const float si = s_sin[am];

  const vfloat4 a = xb[fa];
  const vfloat4 b = xb[fb];

  const vfloat4 oa = co * a - si * b;
  const vfloat4 obv = co * b + si * a;

  __builtin_nontemporal_store(oa, &ob[fa]);
  __builtin_nontemporal_store(obv, &ob[fb]);
}

extern "C" void kernel_launch(void* const* d_in, const int* in_sizes, int n_in,
                              void* d_out, int out_size, void* d_ws, size_t ws_size,
                              hipStream_t stream) {
  const vfloat4* x = (const vfloat4*)d_in[0];
  const float* angle = (const float*)d_in[1];
  vfloat4* out = (vfloat4*)d_out;
  const int N = in_sizes[1];  // one angle per sample

  wigner_z_pair2_kernel<<<N, 512, 0, stream>>>(x, angle, out, N);
}

// Round 5
// 253.354 us; speedup vs baseline: 1.1492x; 1.0786x over previous
//
#include <hip/hip_runtime.h>

typedef float vfloat4 __attribute__((ext_vector_type(4)));

// Irreps l=0..7, DIM=64. 32 generalized pairs:
//  - 28 real pairs (M+ = l^2+l+m, M- = l^2+l-m, m=1..l), rotation angle m*phi.
//  - 4 pseudo-pairs covering the 8 m==0 rows with am=0 (cos=1, sin=0 -> identity).
__constant__ int P_A[32] = {
  3, 7,8, 13,14,15, 21,22,23,24, 31,32,33,34,35,
  43,44,45,46,47,48, 57,58,59,60,61,62,63,
  0, 6, 20, 42
};
__constant__ int P_B[32] = {
  1, 5,4, 11,10,9, 19,18,17,16, 29,28,27,26,25,
  41,40,39,38,37,36, 55,54,53,52,51,50,49,
  2, 12, 30, 56
};
__constant__ float P_AM[32] = {
  1, 1,2, 1,2,3, 1,2,3,4, 1,2,3,4,5, 1,2,3,4,5,6, 1,2,3,4,5,6,7,
  0, 0, 0, 0
};

// One block per sample n. Tile = 64x64 fp32 = 1024 float4.
// 512 threads = 32 pairs x 16 float4-cols; each thread: 2 loads, 2 stores.
// No LDS, no barrier: loads issue immediately; per-thread sincos overlaps
// HBM latency. Uniform control flow; 8-wave blocks -> 32/32 waves/CU.
__global__ __launch_bounds__(512) void wigner_z_pair3_kernel(
    const vfloat4* __restrict__ x, const float* __restrict__ angle,
    vfloat4* __restrict__ out, int N) {
  const int n = blockIdx.x;
  const int t = threadIdx.x;

  const int p = t >> 4;
  const int c4 = t & 15;
  const int fa = (P_A[p] << 4) | c4;
  const int fb = (P_B[p] << 4) | c4;

  const vfloat4* __restrict__ xb = x + (size_t)n * 1024;
  vfloat4* __restrict__ ob = out + (size_t)n * 1024;

  // Issue both streaming loads first; they cover the sincos latency.
  const vfloat4 a = __builtin_nontemporal_load(&xb[fa]);
  const vfloat4 b = __builtin_nontemporal_load(&xb[fb]);

  float si, co;
  sincosf(P_AM[p] * angle[n], &si, &co);  // am==0 -> (0,1): identity rows

  const vfloat4 oa = co * a - si * b;
  const vfloat4 obv = co * b + si * a;

  __builtin_nontemporal_store(oa, &ob[fa]);
  __builtin_nontemporal_store(obv, &ob[fb]);
}

extern "C" void kernel_launch(void* const* d_in, const int* in_sizes, int n_in,
                              void* d_out, int out_size, void* d_ws, size_t ws_size,
                              hipStream_t stream) {
  const vfloat4* x = (const vfloat4*)d_in[0];
  const float* angle = (const float*)d_in[1];
  vfloat4* out = (vfloat4*)d_out;
  const int N = in_sizes[1];  // one angle per sample

  wigner_z_pair3_kernel<<<N, 512, 0, stream>>>(x, angle, out, N);
}